// Round 10
// baseline (336.265 us; speedup 1.0000x reference)
//
#include <hip/hip_runtime.h>
#include <cstdint>
#include <cstddef>

// RNNDec GRU rollout: N=4096, H=512, T=12. R10 = exact R5 (k0 scalar, k1,
// k3 partial-based; proven 295us) with ONE k2 change: A-fragments live in
// VGPRs (direct global loads, software-pipelined 1 chunk ahead), LDS holds
// only B (dbuf 2x24KB, BK=128, 4 barriers/step). Mechanism: removes A from
// the barrier/vmcnt drain path and cuts ds_read issue by 25%.

typedef __attribute__((ext_vector_type(8))) _Float16 f16x8;
typedef __attribute__((ext_vector_type(16))) float floatx16;

__device__ __forceinline__ float sigm_f(float v) { return 1.0f / (1.0f + __expf(-v)); }
__device__ __forceinline__ float tanh_f(float v) { return 2.0f / (1.0f + __expf(-2.0f * v)) - 1.0f; }

__device__ __forceinline__ void async16(void* lds, const void* g) {
    __builtin_amdgcn_global_load_lds(
        (const __attribute__((address_space(1))) void*)g,
        (__attribute__((address_space(3))) void*)lds, 16, 0, 0);
}

// ---------------- K0: casts + packing + a0 (R5 scalar version) ----------------
__global__ __launch_bounds__(256) void k0_prep(
    const float* __restrict__ z, const float* __restrict__ x,
    const float* __restrict__ x0, const float* __restrict__ W_ia,
    const float* __restrict__ b_ia, const float* __restrict__ W_ih,
    const float* __restrict__ W_hh, const float* __restrict__ W_h0,
    const float* __restrict__ W_out, const float* __restrict__ b_hh,
    _Float16* __restrict__ zx16, _Float16* __restrict__ wcat16,
    _Float16* __restrict__ whh16, float* __restrict__ pk, float* __restrict__ xbuf)
{
    const int ZX = 4096 * 256, WC = 2048 * 256, WH = 1536 * 512, PKN = 512, XB = 4096 * 2;
    const int total = ZX + WC + WH + PKN + XB;
    for (int idx = blockIdx.x * 256 + threadIdx.x; idx < total; idx += gridDim.x * 256) {
        if (idx < ZX) {
            int i = idx >> 8, k = idx & 255;
            float v = (k < 128) ? z[i * 128 + k] : x[i * 128 + (k - 128)];
            zx16[idx] = (_Float16)v;
        } else if (idx < ZX + WC) {
            int j = idx - ZX;
            int n = j >> 8, k = j & 255;
            float v = (n < 512) ? W_h0[n * 256 + k] : W_ih[(n - 512) * 258 + k];
            wcat16[j] = (_Float16)v;
        } else if (idx < ZX + WC + WH) {
            int j = idx - ZX - WC;
            whh16[j] = (_Float16)W_hh[j];
        } else if (idx < ZX + WC + WH + PKN) {
            int jc = idx - ZX - WC - WH;
            float* o = pk + jc * 12;
            o[0] = W_ih[jc * 258 + 256];          o[1] = W_ih[jc * 258 + 257];
            o[2] = W_ih[(512 + jc) * 258 + 256];  o[3] = W_ih[(512 + jc) * 258 + 257];
            o[4] = W_ih[(1024 + jc) * 258 + 256]; o[5] = W_ih[(1024 + jc) * 258 + 257];
            o[6] = b_hh[jc]; o[7] = b_hh[512 + jc]; o[8] = b_hh[1024 + jc];
            o[9] = W_out[jc]; o[10] = W_out[512 + jc]; o[11] = 0.f;
        } else {
            int j = idx - ZX - WC - WH - PKN;
            int i = j >> 1, d = j & 1;
            float s = b_ia[d];
            #pragma unroll
            for (int k2 = 0; k2 < 4; k2++) s += x0[i * 4 + k2] * W_ia[d * 4 + k2];
            xbuf[j] = s;
        }
    }
}

// ---------------- K1: h0 (cols 0..511) + gi planes (cols 512..2047), fp16 ----------------
__global__ __launch_bounds__(256) void k1_precompute(
    const _Float16* __restrict__ zx16, const _Float16* __restrict__ wcat16,
    const float* __restrict__ b_h0, const float* __restrict__ b_ih,
    _Float16* __restrict__ h16a, _Float16* __restrict__ gi16)
{
    __shared__ __align__(16) char smem[24576];
    const uint32_t BOFF = 0, AOFF = 8192;
    int tid = threadIdx.x;
    int w = tid >> 6, lane = tid & 63;
    int half = lane >> 5, l31 = lane & 31;
    int rsub = lane >> 3, csub = lane & 7;
    int Mb = blockIdx.x * 128, Nb = blockIdx.y * 64;

    const _Float16* gsrc[6];
    uint32_t ldso[6];
    #pragma unroll
    for (int j = 0; j < 6; j++) {
        int L = w + 4 * j;
        if (L < 16) {
            int r = L * 8 + rsub;
            gsrc[j] = zx16 + (size_t)(Mb + r) * 256 + ((csub ^ (r & 7)) << 3);
            ldso[j] = AOFF + (uint32_t)L * 1024;
        } else {
            int rb = (L - 16) * 8 + rsub;
            gsrc[j] = wcat16 + (size_t)(Nb + rb) * 256 + ((csub ^ (rb & 7)) << 3);
            ldso[j] = BOFF + (uint32_t)(L - 16) * 1024;
        }
    }

    floatx16 acc0 = {0,0,0,0,0,0,0,0,0,0,0,0,0,0,0,0};
    floatx16 acc1 = {0,0,0,0,0,0,0,0,0,0,0,0,0,0,0,0};

    for (int kc = 0; kc < 4; kc++) {
        #pragma unroll
        for (int j = 0; j < 6; j++) async16(smem + ldso[j], gsrc[j] + kc * 64);
        __syncthreads();
        #pragma unroll
        for (int ks = 0; ks < 4; ks++) {
            int ch = ks * 2 + half;
            int ar = (w << 5) | l31;
            f16x8 a = *(const f16x8*)(smem + AOFF + ((uint32_t)ar << 7) + ((uint32_t)(ch ^ (ar & 7)) << 4));
            uint32_t sw = (uint32_t)(ch ^ (l31 & 7)) << 4;
            f16x8 b0 = *(const f16x8*)(smem + BOFF + ((uint32_t)l31 << 7) + sw);
            f16x8 b1 = *(const f16x8*)(smem + BOFF + ((uint32_t)(32 + l31) << 7) + sw);
            acc0 = __builtin_amdgcn_mfma_f32_32x32x16_f16(a, b0, acc0, 0, 0, 0);
            acc1 = __builtin_amdgcn_mfma_f32_32x32x16_f16(a, b1, acc1, 0, 0, 0);
        }
        __syncthreads();
    }

    #pragma unroll
    for (int nt = 0; nt < 2; nt++) {
        int ncol = Nb + nt * 32 + l31;
        floatx16 acc = nt ? acc1 : acc0;
        #pragma unroll
        for (int reg = 0; reg < 16; reg++) {
            int row = (reg & 3) + 8 * (reg >> 2) + 4 * half;
            size_t i = (size_t)Mb + (w << 5) + row;
            float v = acc[reg];
            if (ncol < 512) {
                h16a[i * 512 + ncol] = (_Float16)(v + b_h0[ncol]);
            } else {
                int c = ncol - 512;
                int g = c >> 9, jc = c & 511;
                gi16[(size_t)g * 2097152 + i * 512 + jc] = (_Float16)(v + b_ih[c]);
            }
        }
    }
}

// ---------------- K2: one GRU step (A-in-registers, B-only LDS dbuf) ----------------
// Tile 128m x (32 jc x 3 gates). grid (32,16), 256 thr = 4 waves.
// A: wave w owns rows w*32+l31; per BK=128 chunk 8 x f16x8 VGPR, prefetched
// one chunk ahead (drained by the same vmcnt(0) the barrier needs anyway).
// B: LDS dbuf 2 x 24KB; layout rb*256 + 16*(granule ^ (rb&15)) -> b128
// conflict-free reads, coalesced wave-uniform-base async16 staging.
__global__ __launch_bounds__(256, 2) void k2_step(
    int t,
    const _Float16* __restrict__ hin, _Float16* __restrict__ hout,
    const _Float16* __restrict__ whh16, const _Float16* __restrict__ gi16,
    const float* __restrict__ pk, const float* __restrict__ xbuf,
    float* __restrict__ partial, float* __restrict__ dout,
    const float* __restrict__ b_out)
{
    __shared__ __align__(16) char smem[50176];
    const uint32_t PROD = 0;       // epilogue overlay [128][32][2] f32 = 32768
    const uint32_t XS = 49152;     // [128][2] f32 = 1024
    int tid = threadIdx.x;
    int bx = blockIdx.x, by = blockIdx.y;
    int Mbase = bx * 128, Jbase = by * 32;
    int w = tid >> 6, lane = tid & 63;
    int half = lane >> 5, l31 = lane & 31;
    float* xs = (float*)(smem + XS);  // [128][2]

    // B staging descriptors: issue e = w + 4*jj covers rows 4e..4e+3.
    // Lane l -> row rb = 4e + (l>>4), LDS granule gs = l&15 holds global
    // granule gg = gs ^ (rb&15).
    const _Float16* srcB[6];
    uint32_t dstB[6];
    #pragma unroll
    for (int jj = 0; jj < 6; jj++) {
        int e = w + 4 * jj;
        int rb = 4 * e + (lane >> 4);
        int gg = (lane & 15) ^ (rb & 15);
        int jrow = (rb >> 5) * 512 + Jbase + (rb & 31);
        srcB[jj] = whh16 + (size_t)jrow * 512 + gg * 8;
        dstB[jj] = (uint32_t)e * 1024;          // wave-uniform; HW adds lane*16
    }

    // A base: wave w, lane pair (half,l31) owns row w*32+l31, 16B at half*8
    const _Float16* abase = hin + (size_t)(Mbase + (w << 5) + l31) * 512 + half * 8;

    f16x8 acur[8], anxt[8];
    // chunk 0: stage B -> buf0, load A regs
    #pragma unroll
    for (int jj = 0; jj < 6; jj++) async16(smem + dstB[jj], srcB[jj]);
    #pragma unroll
    for (int ks = 0; ks < 8; ks++) acur[ks] = *(const f16x8*)(abase + ks * 16);

    // prologue: x_t for this block's 128 samples (and write out_{t-1})
    {
        int i = tid >> 1, d = tid & 1;
        float v;
        if (t == 0) {
            v = xbuf[(size_t)(Mbase + i) * 2 + d];
        } else {
            const float4* p = (const float4*)(partial + ((size_t)(Mbase + i) * 2 + d) * 16);
            float4 a = p[0], b = p[1], c = p[2], e = p[3];
            v = b_out[d] + a.x + a.y + a.z + a.w + b.x + b.y + b.z + b.w
                         + c.x + c.y + c.z + c.w + e.x + e.y + e.z + e.w;
            if (by == 0) dout[((size_t)(Mbase + i) * 12 + (t - 1)) * 2 + d] = v;
        }
        xs[i * 2 + d] = v;
    }

    floatx16 accR = {0,0,0,0,0,0,0,0,0,0,0,0,0,0,0,0};
    floatx16 accZ = {0,0,0,0,0,0,0,0,0,0,0,0,0,0,0,0};
    floatx16 accN = {0,0,0,0,0,0,0,0,0,0,0,0,0,0,0,0};

    __syncthreads();   // B0 staged, A0 in regs, xs published

    #pragma unroll
    for (int c = 0; c < 4; c++) {
        if (c < 3) {
            // prefetch chunk c+1: B -> alternate buf, A -> anxt (both drained
            // by the compiler's vmcnt(0) at the chunk-end barrier)
            #pragma unroll
            for (int jj = 0; jj < 6; jj++)
                async16(smem + ((uint32_t)((c + 1) & 1) * 24576) + dstB[jj],
                        srcB[jj] + (c + 1) * 128);
            #pragma unroll
            for (int ks = 0; ks < 8; ks++)
                anxt[ks] = *(const f16x8*)(abase + (c + 1) * 128 + ks * 16);
        }
        uint32_t bb = (uint32_t)(c & 1) * 24576;
        #pragma unroll
        for (int ks = 0; ks < 8; ks++) {
            uint32_t sw = (uint32_t)(((2 * ks + half) ^ (l31 & 15)) << 4);
            f16x8 b0 = *(const f16x8*)(smem + bb + ((uint32_t)l31 << 8) + sw);
            f16x8 b1 = *(const f16x8*)(smem + bb + ((uint32_t)(32 + l31) << 8) + sw);
            f16x8 b2 = *(const f16x8*)(smem + bb + ((uint32_t)(64 + l31) << 8) + sw);
            accR = __builtin_amdgcn_mfma_f32_32x32x16_f16(acur[ks], b0, accR, 0, 0, 0);
            accZ = __builtin_amdgcn_mfma_f32_32x32x16_f16(acur[ks], b1, accZ, 0, 0, 0);
            accN = __builtin_amdgcn_mfma_f32_32x32x16_f16(acur[ks], b2, accN, 0, 0, 0);
        }
        __syncthreads();
        if (c < 3) {
            #pragma unroll
            for (int ks = 0; ks < 8; ks++) acur[ks] = anxt[ks];
        }
    }

    // epilogue: gates + state update; out-partials in LDS (overlay B region)
    float* prod = (float*)(smem + PROD);  // [128][32][2] fp32 = 32 KB
    int jcg = Jbase + l31;
    const float4* pkp = (const float4*)(pk + (size_t)jcg * 12);
    float4 p0 = pkp[0], p1 = pkp[1], p2 = pkp[2];
    // p0={wxr0,wxr1,wxz0,wxz1} p1={wxn0,wxn1,bhr,bhz} p2={bhn,wo0,wo1,-}
    const _Float16* giR = gi16;
    const _Float16* giZ = gi16 + 2097152;
    const _Float16* giN = gi16 + 4194304;
    #pragma unroll
    for (int reg = 0; reg < 16; reg++) {
        int row = (reg & 3) + 8 * (reg >> 2) + 4 * half;
        int iloc = (w << 5) + row;
        size_t i = (size_t)Mbase + iloc;
        float g0 = (float)giR[i * 512 + jcg];
        float g1 = (float)giZ[i * 512 + jcg];
        float g2v = (float)giN[i * 512 + jcg];
        float x0 = xs[iloc * 2], x1 = xs[iloc * 2 + 1];
        float r = sigm_f(g0 + p0.x * x0 + p0.y * x1 + accR[reg] + p1.z);
        float u = sigm_f(g1 + p0.z * x0 + p0.w * x1 + accZ[reg] + p1.w);
        float nn = tanh_f(g2v + p1.x * x0 + p1.y * x1 + r * (accN[reg] + p2.x));
        float hold = (float)hin[i * 512 + jcg];
        float hn = (1.f - u) * nn + u * hold;
        hout[i * 512 + jcg] = (_Float16)hn;
        ((float2*)prod)[iloc * 32 + l31] = make_float2(hn * p2.y, hn * p2.z);
    }
    __syncthreads();
    {
        int i = tid >> 1, d = tid & 1;
        float s = 0.f;
        #pragma unroll
        for (int jj = 0; jj < 32; jj++) {
            int jc = (jj + i) & 31;   // skew to avoid bank conflicts
            s += prod[(i * 32 + jc) * 2 + d];
        }
        partial[((size_t)(Mbase + i) * 2 + d) * 16 + by] = s;
    }
}

// ---------------- K3: final output out_11 (R5 partial-based) ----------------
__global__ __launch_bounds__(256) void k3_final(
    const float* __restrict__ partial, const float* __restrict__ b_out,
    float* __restrict__ dout)
{
    int gid = blockIdx.x * 256 + threadIdx.x;
    if (gid < 8192) {
        int i = gid >> 1, d = gid & 1;
        const float4* p = (const float4*)(partial + ((size_t)i * 2 + d) * 16);
        float4 a = p[0], b = p[1], c = p[2], e = p[3];
        float v = b_out[d] + a.x + a.y + a.z + a.w + b.x + b.y + b.z + b.w
                           + c.x + c.y + c.z + c.w + e.x + e.y + e.z + e.w;
        dout[((size_t)i * 12 + 11) * 2 + d] = v;
    }
}

extern "C" void kernel_launch(void* const* d_in, const int* in_sizes, int n_in,
                              void* d_out, int out_size, void* d_ws, size_t ws_size,
                              hipStream_t stream)
{
    const float* z     = (const float*)d_in[0];
    const float* x     = (const float*)d_in[1];
    const float* x0    = (const float*)d_in[2];
    const float* W_ia  = (const float*)d_in[3];
    const float* b_ia  = (const float*)d_in[4];
    const float* W_h0  = (const float*)d_in[5];
    const float* b_h0  = (const float*)d_in[6];
    const float* W_ih  = (const float*)d_in[7];
    const float* b_ih  = (const float*)d_in[8];
    const float* W_hh  = (const float*)d_in[9];
    const float* b_hh  = (const float*)d_in[10];
    const float* W_out = (const float*)d_in[11];
    const float* b_out = (const float*)d_in[12];
    float* dout = (float*)d_out;

    char* ws = (char*)d_ws;
    _Float16* h16a   = (_Float16*)(ws + 0);          // 4 MiB
    _Float16* h16b   = (_Float16*)(ws + 4194304);    // 4 MiB
    _Float16* gi16   = (_Float16*)(ws + 8388608);    // 3 planes x 4096*512 fp16 = 12 MiB
    _Float16* zx16   = (_Float16*)(ws + 20971520);   // 2 MiB
    _Float16* wcat16 = (_Float16*)(ws + 23068672);   // 1 MiB
    _Float16* whh16  = (_Float16*)(ws + 24117248);   // 1.5 MiB
    float*    pk     = (float*)(ws + 25690112);      // 24 KiB
    float*    xbuf   = (float*)(ws + 25714688);      // 32 KiB
    float*    partial= (float*)(ws + 25747456);      // 512 KiB

    k0_prep<<<2048, 256, 0, stream>>>(z, x, x0, W_ia, b_ia, W_ih, W_hh, W_h0,
                                      W_out, b_hh, zx16, wcat16, whh16, pk, xbuf);
    k1_precompute<<<dim3(32, 32), 256, 0, stream>>>(zx16, wcat16, b_h0, b_ih, h16a, gi16);
    for (int t = 0; t < 12; t++) {
        _Float16* hin  = (t & 1) ? h16b : h16a;
        _Float16* hout = (t & 1) ? h16a : h16b;
        k2_step<<<dim3(32, 16), 256, 0, stream>>>(t, hin, hout, whh16, gi16,
                                                  pk, xbuf, partial, dout, b_out);
    }
    k3_final<<<32, 256, 0, stream>>>(partial, b_out, dout);
}